// Round 1
// baseline (84.810 us; speedup 1.0000x reference)
//
#include <hip/hip_runtime.h>

#define IN_DIM 128
#define OUT_DIM 128
#define BATCH 512
#define NKNOT 12             // G + 2K + 1
#define NB 8                 // G + K spline coeffs
#define KF 9                 // features per input dim: silu + 8 basis
#define BM 32
#define BN 64
#define CI 8                 // input dims per k-chunk
#define CK (CI * KF)         // 72
#define NSPLIT (IN_DIM / CI) // 16
#define APAD 36              // As row stride (16B-aligned, <=2-way bank aliasing)
#define BPAD 68              // Bs row stride (16B-aligned, <=2-way bank aliasing)

// One fused dispatch, 512 blocks (2/CU -> 8 waves/CU for latency hiding):
// per block build weight tile from raw params (LDS transpose), feature tile
// from x (division-free Cox-de Boor: uniform knots -> one rcp), 2x4 microtile
// GEMM, hardware-atomic split-K reduce into out (z==0 blocks add bias).
//
// Idempotency: kernel_launch zeroes d_out with a 256-KB hipMemsetAsync before
// the dispatch, so the iteration is self-contained (no dependence on the
// harness's pre-iteration poison state -> no per-iteration re-poison needed
// in the timed loop).
__global__ __launch_bounds__(256) void kan_fused(
    const float* __restrict__ x, const float* __restrict__ gridk,
    const float* __restrict__ coeff, const float* __restrict__ mask,
    const float* __restrict__ sbase, const float* __restrict__ sspl,
    const float* __restrict__ bias, float* __restrict__ out)
{
    __shared__ float As[CK * APAD]; // features [kk][bl]  10368 B
    __shared__ float Bs[CK * BPAD]; // weights  [kk][n]   19584 B

    const int tid = threadIdx.x;
    const int bn0 = blockIdx.x * BN;
    const int bm0 = blockIdx.y * BM;
    const int i0  = blockIdx.z * CI;

    // ---- weight tile Bs[kk][n], kk = il*9 + j. il-minor lanes -> coeff
    // reads are contiguous 32B/lane; mask/sb/ss are 8x32B segments/wave.
    for (int tt = tid; tt < BN * CI; tt += 256) {
        int il = tt & (CI - 1);
        int n  = tt >> 3;
        int s  = (bn0 + n) * IN_DIM + i0 + il;
        float m  = mask[s];
        float wb = m * sbase[s];
        float ws = m * sspl[s];
        const float4* cp = (const float4*)(coeff + (size_t)s * NB);
        float4 c0 = cp[0], c1 = cp[1];
        int r = il * KF;
        Bs[(r + 0) * BPAD + n] = wb;
        Bs[(r + 1) * BPAD + n] = ws * c0.x;
        Bs[(r + 2) * BPAD + n] = ws * c0.y;
        Bs[(r + 3) * BPAD + n] = ws * c0.z;
        Bs[(r + 4) * BPAD + n] = ws * c0.w;
        Bs[(r + 5) * BPAD + n] = ws * c1.x;
        Bs[(r + 6) * BPAD + n] = ws * c1.y;
        Bs[(r + 7) * BPAD + n] = ws * c1.z;
        Bs[(r + 8) * BPAD + n] = ws * c1.w;
    }

    // ---- feature tile As[kk][bl]: exactly 256 items -> one pass.
    {
        int il = tid & (CI - 1);
        int bl = tid >> 3;          // 0..31
        int i  = i0 + il;
        float xv = x[(bm0 + bl) * IN_DIM + i];
        const float* g = gridk + i * NKNOT;
        float gr[NKNOT];
        #pragma unroll
        for (int t = 0; t < NKNOT; ++t) gr[t] = g[t];

        float inv1 = __builtin_amdgcn_rcpf(gr[1] - gr[0]);
        float inv2 = inv1 * 0.5f;
        float inv3 = inv1 * (1.0f / 3.0f);

        float bs[NKNOT - 1];
        #pragma unroll
        for (int t = 0; t < NKNOT - 1; ++t)
            bs[t] = (xv >= gr[t] && xv < gr[t + 1]) ? 1.0f : 0.0f;
        #pragma unroll
        for (int t = 0; t < NKNOT - 2; ++t)
            bs[t] = (xv - gr[t]) * inv1 * bs[t] + (gr[t + 2] - xv) * inv1 * bs[t + 1];
        #pragma unroll
        for (int t = 0; t < NKNOT - 3; ++t)
            bs[t] = (xv - gr[t]) * inv2 * bs[t] + (gr[t + 3] - xv) * inv2 * bs[t + 1];
        #pragma unroll
        for (int t = 0; t < NKNOT - 4; ++t)
            bs[t] = (xv - gr[t]) * inv3 * bs[t] + (gr[t + 4] - xv) * inv3 * bs[t + 1];

        float sig = 1.0f / (1.0f + __expf(-xv));
        int r = il * KF;
        As[(r + 0) * APAD + bl] = xv * sig;
        #pragma unroll
        for (int c = 0; c < NB; ++c)
            As[(r + 1 + c) * APAD + bl] = bs[c];
    }
    __syncthreads();

    // ---- 2x4 microtile GEMM over CK=72.
    const int tx = tid & 15;   // n: 4 cols
    const int ty = tid >> 4;   // m: 2 rows (0..15)
    float acc[2][4] = {};
    #pragma unroll 8
    for (int kk = 0; kk < CK; ++kk) {
        float2 a = *(const float2*)&As[kk * APAD + ty * 2];
        float4 b = *(const float4*)&Bs[kk * BPAD + tx * 4];
        float av[2] = {a.x, a.y};
        float bv[4] = {b.x, b.y, b.z, b.w};
        #pragma unroll
        for (int r = 0; r < 2; ++r)
            #pragma unroll
            for (int c = 0; c < 4; ++c)
                acc[r][c] += av[r] * bv[c];
    }

    // ---- epilogue: z==0 carries bias; hardware fp32 atomics for split-K.
    if (blockIdx.z == 0) {
        #pragma unroll
        for (int c = 0; c < 4; ++c) {
            float bv = bias[bn0 + tx * 4 + c];
            #pragma unroll
            for (int r = 0; r < 2; ++r) acc[r][c] += bv;
        }
    }
    float* op = out + (size_t)(bm0 + ty * 2) * OUT_DIM + bn0 + tx * 4;
    #pragma unroll
    for (int r = 0; r < 2; ++r)
        #pragma unroll
        for (int c = 0; c < 4; ++c)
            unsafeAtomicAdd(&op[r * OUT_DIM + c], acc[r][c]);
}

extern "C" void kernel_launch(void* const* d_in, const int* in_sizes, int n_in,
                              void* d_out, int out_size, void* d_ws, size_t ws_size,
                              hipStream_t stream)
{
    const float* x     = (const float*)d_in[0];
    const float* grid  = (const float*)d_in[1];
    const float* coeff = (const float*)d_in[2];
    const float* mask  = (const float*)d_in[3];
    const float* sb    = (const float*)d_in[4];
    const float* ss    = (const float*)d_in[5];
    const float* bias  = (const float*)d_in[6];
    float* out = (float*)d_out;

    // Self-contained iteration: zero the 256-KB output (stream-ordered,
    // graph-capturable; ~0.04 us at HBM BW) so the split-K atomic accumulate
    // does not depend on pre-launch buffer contents.
    hipMemsetAsync(out, 0, (size_t)BATCH * OUT_DIM * sizeof(float), stream);

    dim3 g(OUT_DIM / BN, BATCH / BM, NSPLIT); // (2, 16, 16) = 512 blocks
    kan_fused<<<g, 256, 0, stream>>>(x, grid, coeff, mask, sb, ss, bias, out);
}